// Round 3
// baseline (5727.817 us; speedup 1.0000x reference)
//
#include <hip/hip_runtime.h>
#include <hip/hip_bf16.h>
#include <hip/hip_cooperative_groups.h>

namespace cg = cooperative_groups;

typedef short short8 __attribute__((ext_vector_type(8)));
typedef float floatx4 __attribute__((ext_vector_type(4)));

#define B_ 64
#define L_ 196
#define T_ 31
#define PRED_ 19840000ULL

__device__ __forceinline__ float bf2f(unsigned short u){
  union { unsigned int i; float f; } v; v.i = ((unsigned int)u)<<16; return v.f;
}
__device__ __forceinline__ float lo16(unsigned int u){
  union { unsigned int i; float f; } v; v.i = u << 16; return v.f;
}
__device__ __forceinline__ float hi16(unsigned int u){
  union { unsigned int i; float f; } v; v.i = u & 0xffff0000u; return v.f;
}
__device__ __forceinline__ unsigned int pk2(float a, float b){
  union { __hip_bfloat16 h; unsigned short u; } x, y;
  x.h = __float2bfloat16(a); y.h = __float2bfloat16(b);
  return (unsigned int)x.u | ((unsigned int)y.u << 16);
}
__device__ __forceinline__ float sigm(float x){ return 1.0f/(1.0f+__expf(-x)); }

// ---------------- cast f32 -> bf16 (vector x4) ----------------
__global__ __launch_bounds__(256) void k_cast(const float* __restrict__ src,
                                              __hip_bfloat16* __restrict__ dst, int n4){
  int i = blockIdx.x*256 + threadIdx.x;
  if (i < n4){
    const float4 v = *(const float4*)(src + (size_t)i*4);
    size_t o = (size_t)i*4;
    dst[o+0] = __float2bfloat16(v.x);
    dst[o+1] = __float2bfloat16(v.y);
    dst[o+2] = __float2bfloat16(v.z);
    dst[o+3] = __float2bfloat16(v.w);
  }
}

// ------- tiled transpose: src (Kin x Nin) -> dst[n][k] bf16, row stride S --------
__global__ __launch_bounds__(1024) void k_trans_bf16(const float* __restrict__ src,
    __hip_bfloat16* __restrict__ dst, int Kin, int Nin, int S, int Rtot){
  __shared__ float tile[32][33];
  int n0 = blockIdx.x*32, k0 = blockIdx.y*32;
  int x = threadIdx.x & 31, y = threadIdx.x >> 5;
  int k = k0 + y, nn = n0 + x;
  tile[y][x] = (k < Kin && nn < Nin) ? src[(size_t)k*Nin + nn] : 0.0f;
  __syncthreads();
  int n2 = n0 + y, k2 = k0 + x;
  if (n2 < Rtot && k2 < Kin) dst[(size_t)n2*S + k2] = __float2bfloat16(tile[x][y]);
}

// ---------------- embedding gather: Erow[(t*64+b)][m] bf16 -------
__global__ __launch_bounds__(512) void k_emb(const int* __restrict__ captions,
    const float* __restrict__ emb, __hip_bfloat16* __restrict__ Erow){
  int tb = blockIdx.x; int t = tb >> 6; int b = tb & 63; int m = threadIdx.x;
  int cap = captions[b*32 + t];
  Erow[((size_t)(t*64 + b))*512 + m] = __float2bfloat16(emb[(size_t)cap*512 + m]);
}

// ---------------- init h0/c0 (one block per b) ----------------
__global__ __launch_bounds__(512) void k_init(const float* __restrict__ enc,
    const float* __restrict__ Whi, const float* __restrict__ bhi,
    const float* __restrict__ Wci, const float* __restrict__ bci,
    float* __restrict__ hT, float* __restrict__ cT, unsigned int* __restrict__ hP){
  int b = blockIdx.x; int d = threadIdx.x;
  __shared__ float ms[512];
  __shared__ float hs[512];
  const float* eb = enc + (size_t)b*L_*512;
  float s = 0.f;
  for (int l = 0; l < L_; l++) s += eb[(size_t)l*512 + d];
  ms[d] = s * (1.0f/196.0f);
  __syncthreads();
  float a1 = bhi[d], a2 = bci[d];
  #pragma unroll 4
  for (int k = 0; k < 512; k++){
    float mv = ms[k];
    a1 += mv * Whi[(size_t)k*512 + d];
    a2 += mv * Wci[(size_t)k*512 + d];
  }
  float h = tanhf(a1);
  hT[d*64 + b] = h;
  cT[d*64 + b] = tanhf(a2);
  hs[d] = h;
  __syncthreads();
  if (d < 256) hP[d*64 + b] = pk2(hs[2*d], hs[2*d+1]);
}

// ---------------- MFMA bf16 GEMM: C(64x64 tiles) = A(MxK) @ Bt(NxK)^T ----------------
// mode 0: att1T  -> outB bf16 at [b][c][l] (r -> b=r/196, l=r%196), += bias1[c]
// mode 1: U      -> outB bf16 = acc + bias1[c] + bias2[c] + Erow[r][c]
// mode 2: logits -> outF f32  = mask(t<dec_len) * (acc + bias1[c]) at [b][t][c]
// mode 3: preIH  -> outB bf16 at [t][c][b] (r -> t=r>>6, b=r&63)
__global__ __launch_bounds__(256) void k_gemm(const __hip_bfloat16* __restrict__ Abf,
    const __hip_bfloat16* __restrict__ Bt, int K, int mode, int Nreal,
    const float* __restrict__ bias1, const float* __restrict__ bias2,
    const __hip_bfloat16* __restrict__ Erow, const int* __restrict__ caplen,
    __hip_bfloat16* __restrict__ outB, float* __restrict__ outF){
  int lane = threadIdx.x & 63; int wv = threadIdx.x >> 6;
  int wr = wv >> 1, wc = wv & 1;
  int r0 = blockIdx.y*64 + wr*32;
  int c0 = blockIdx.x*64 + wc*32;
  int l15 = lane & 15, lg = lane >> 4;
  const short* Ap = (const short*)Abf;
  const short* Bp = (const short*)Bt;
  floatx4 acc00 = {0,0,0,0}, acc01 = {0,0,0,0}, acc10 = {0,0,0,0}, acc11 = {0,0,0,0};
  size_t ar0 = (size_t)(r0 + l15)*K + lg*8;
  size_t ar1 = ar0 + (size_t)16*K;
  size_t br0 = (size_t)(c0 + l15)*K + lg*8;
  size_t br1 = br0 + (size_t)16*K;
  #pragma unroll 4
  for (int k0 = 0; k0 < K; k0 += 32){
    short8 av0 = *(const short8*)(Ap + ar0 + k0);
    short8 av1 = *(const short8*)(Ap + ar1 + k0);
    short8 bv0 = *(const short8*)(Bp + br0 + k0);
    short8 bv1 = *(const short8*)(Bp + br1 + k0);
    acc00 = __builtin_amdgcn_mfma_f32_16x16x32_bf16(av0, bv0, acc00, 0, 0, 0);
    acc01 = __builtin_amdgcn_mfma_f32_16x16x32_bf16(av0, bv1, acc01, 0, 0, 0);
    acc10 = __builtin_amdgcn_mfma_f32_16x16x32_bf16(av1, bv0, acc10, 0, 0, 0);
    acc11 = __builtin_amdgcn_mfma_f32_16x16x32_bf16(av1, bv1, acc11, 0, 0, 0);
  }
  floatx4 accs[2][2] = {{acc00, acc01}, {acc10, acc11}};
  #pragma unroll
  for (int i = 0; i < 2; i++){
    #pragma unroll
    for (int j = 0; j < 2; j++){
      #pragma unroll
      for (int v = 0; v < 4; v++){
        int r = r0 + 16*i + lg*4 + v;
        int c = c0 + 16*j + l15;
        float val = accs[i][j][v];
        if (mode == 0){
          unsigned int bq = ((unsigned int)r * 21400u) >> 22;  // r/196, valid r<43690
          int l = r - (int)bq*196;
          outB[((size_t)bq*512 + c)*196 + l] = __float2bfloat16(val + bias1[c]);
        } else if (mode == 1){
          float e = bf2f(((const unsigned short*)Erow)[(size_t)r*512 + c]);
          outB[(size_t)r*512 + c] = __float2bfloat16(val + bias1[c] + bias2[c] + e);
        } else if (mode == 2){
          if (c < Nreal){
            int t = r >> 6, b = r & 63;
            float mf = (t < caplen[b] - 1) ? 1.f : 0.f;
            outF[((size_t)b*T_ + t)*10000 + c] = (val + bias1[c]) * mf;
          }
        } else {
          outB[((size_t)(r >> 6)*2048 + c)*64 + (r & 63)] = __float2bfloat16(val);
        }
      }
    }
  }
}

// ============ persistent cooperative kernel: the full 31-step recurrence ============
// 256 blocks x 256 threads.  Block roles:
//   A : rows ab_base..+3 of [att2(512)|beta(512)] + 8 W_hh rows {g*512+n0+j}
//   B : attention for batch bb = blk>>2, quarter qq = blk&3 (49 l's each)
//   C : gates for n' = {n0, n0+1}; c/h state persistent in LDS
__global__ __launch_bounds__(256, 1) void k_loop(
    const __hip_bfloat16* __restrict__ W1Tbf,   // [3072][512] att2|beta|whh
    const __hip_bfloat16* __restrict__ WihzT,   // [2048][512]
    const __hip_bfloat16* __restrict__ preIH,   // [31][2048][64]
    const __hip_bfloat16* __restrict__ att1T,   // [64][512][196]
    const __hip_bfloat16* __restrict__ enc_bf,  // [64][196][512]
    const float* __restrict__ wfa,
    const float* __restrict__ b_da, const float* __restrict__ b_fb,
    const float* __restrict__ b_ih, const float* __restrict__ b_hh,
    const float* __restrict__ hT0, const float* __restrict__ cT0,   // [512][64]
    unsigned int* __restrict__ hP,  // [256][64] packed bf16 pairs (k,k+1)
    unsigned int* __restrict__ zP,  // [256][64]
    float* __restrict__ att2g,      // [512][64]
    float* __restrict__ betag,      // [512][64]
    float* __restrict__ zpart,      // [64][4][512]
    float* __restrict__ msq,        // [64][4][2]
    __hip_bfloat16* __restrict__ HZ,// [1984][1024]
    const int* __restrict__ caplen,
    float* __restrict__ outAlpha)
{
  cg::grid_group grid = cg::this_grid();
  int tid = threadIdx.x, lane = tid & 63, w = tid >> 6;
  int blk = blockIdx.x;
  int n0 = blk*2;
  int ab_base = blk*4;
  int ab_row = ab_base + w;           // [0,1024)
  int bb = blk >> 2, qq = blk & 3;

  __shared__ float wAB[4][512];
  __shared__ float wHH[8][512];
  __shared__ float wZ[8][512];
  __shared__ float wfa_l[512];
  __shared__ float att2c[512];
  __shared__ float eacc[4][64];
  __shared__ float p_l[64];
  __shared__ float glds[4][2][64];
  __shared__ float hst[2][64], cst[2][64];
  __shared__ float bsum[4][2];

  // ---- one-time staging ----
  const short* w1s = (const short*)W1Tbf;
  const short* wzs = (const short*)WihzT;
  for (int i = tid; i < 2048; i += 256)
    ((float*)wAB)[i] = bf2f((unsigned short)w1s[(size_t)ab_base*512 + i]);
  for (int i = tid; i < 4096; i += 256){
    int g = i >> 10, j = (i >> 9) & 1, k = i & 511;
    ((float*)wHH)[i] = bf2f((unsigned short)w1s[(size_t)(1024 + g*512 + n0 + j)*512 + k]);
    ((float*)wZ)[i]  = bf2f((unsigned short)wzs[(size_t)(g*512 + n0 + j)*512 + k]);
  }
  for (int i = tid; i < 512; i += 256) wfa_l[i] = wfa[i];
  if (tid < 128){ int j = tid >> 6;
    hst[j][lane] = hT0[(n0+j)*64 + lane];
    cst[j][lane] = cT0[(n0+j)*64 + lane];
  }
  if (tid < 8){ int g = tid >> 1, j = tid & 1;
    bsum[g][j] = b_ih[g*512 + n0 + j] + b_hh[g*512 + n0 + j];
  }
  int dl  = caplen[lane] - 1;
  int dlb = caplen[bb] - 1;
  float biasAB = (ab_row < 512) ? b_da[ab_row] : b_fb[ab_row - 512];
  __syncthreads();

  float whh0 = 0.f, whh1 = 0.f;

  for (int t = 0; t < T_; t++){
    // ================= Phase A : h-matvecs =================
    {
      const float4* wa4 = (const float4*)&wAB[w][0];
      const float4* w04 = (const float4*)&wHH[w*2+0][0];
      const float4* w14 = (const float4*)&wHH[w*2+1][0];
      float ab = 0.f, ga = 0.f, gb = 0.f;
      #pragma unroll 4
      for (int k4 = 0; k4 < 128; k4++){
        float4 a  = wa4[k4];
        float4 c0 = w04[k4];
        float4 c1 = w14[k4];
        unsigned int u0 = hP[(k4*2+0)*64 + lane];
        unsigned int u1 = hP[(k4*2+1)*64 + lane];
        float h0 = lo16(u0), h1 = hi16(u0), h2 = lo16(u1), h3 = hi16(u1);
        ab += h0*a.x  + h1*a.y  + h2*a.z  + h3*a.w;
        ga += h0*c0.x + h1*c0.y + h2*c0.z + h3*c0.w;
        gb += h0*c1.x + h1*c1.y + h2*c1.z + h3*c1.w;
      }
      if (ab_row < 512) att2g[ab_row*64 + lane] = ab + biasAB;
      else              betag[(ab_row-512)*64 + lane] = ab + biasAB;
      whh0 = ga; whh1 = gb;
    }
    grid.sync();

    // ================= Phase B1 : e + online-softmax partials + zpart =================
    for (int i = tid; i < 512; i += 256) att2c[i] = att2g[i*64 + bb];
    __syncthreads();
    {
      float e = 0.f;
      if (lane < 49){
        const short* arow = (const short*)att1T + ((size_t)bb*512 + w*128)*196 + qq*49 + lane;
        #pragma unroll 4
        for (int a = 0; a < 128; a++){
          float v = bf2f((unsigned short)arow[(size_t)a*196]) + att2c[w*128 + a];
          v = fmaxf(v, 0.f);
          e += v * wfa_l[w*128 + a];
        }
      }
      eacc[w][lane] = e;
    }
    __syncthreads();
    if (w == 0){
      float ee = eacc[0][lane] + eacc[1][lane] + eacc[2][lane] + eacc[3][lane];
      float m = (lane < 49) ? ee : -3e38f;
      #pragma unroll
      for (int off = 32; off; off >>= 1) m = fmaxf(m, __shfl_xor(m, off, 64));
      float pe = (lane < 49) ? __expf(ee - m) : 0.f;
      float s = pe;
      #pragma unroll
      for (int off = 32; off; off >>= 1) s += __shfl_xor(s, off, 64);
      p_l[lane] = pe;
      if (lane == 0){ msq[(bb*4+qq)*2+0] = m; msq[(bb*4+qq)*2+1] = s; }
    }
    __syncthreads();
    {
      float z0 = 0.f, z1 = 0.f;
      const short* ebase = (const short*)enc_bf + ((size_t)bb*196 + qq*49)*512;
      #pragma unroll 2
      for (int l = 0; l < 49; l++){
        float pl = p_l[l];
        z0 += pl * bf2f((unsigned short)ebase[(size_t)l*512 + tid]);
        z1 += pl * bf2f((unsigned short)ebase[(size_t)l*512 + tid + 256]);
      }
      zpart[(size_t)(bb*4+qq)*512 + tid]       = z0;
      zpart[(size_t)(bb*4+qq)*512 + tid + 256] = z1;
    }
    grid.sync();

    // ================= Phase B2 : combine z, write alphas =================
    {
      float m0 = msq[(bb*4+0)*2], s0 = msq[(bb*4+0)*2+1];
      float m1 = msq[(bb*4+1)*2], s1 = msq[(bb*4+1)*2+1];
      float m2 = msq[(bb*4+2)*2], s2 = msq[(bb*4+2)*2+1];
      float m3 = msq[(bb*4+3)*2], s3 = msq[(bb*4+3)*2+1];
      float M = fmaxf(fmaxf(m0,m1), fmaxf(m2,m3));
      float c0 = __expf(m0-M), c1 = __expf(m1-M), c2 = __expf(m2-M), c3 = __expf(m3-M);
      float inv = 1.f / (s0*c0 + s1*c1 + s2*c2 + s3*c3);
      float mf = (t < dlb) ? 1.f : 0.f;
      if (tid < 49){
        float cq = (qq==0) ? c0 : (qq==1) ? c1 : (qq==2) ? c2 : c3;
        outAlpha[((size_t)bb*T_ + t)*196 + qq*49 + tid] = p_l[tid] * cq * inv * mf;
      }
      if (tid < 64){
        int d2 = qq*64 + tid;
        int d = d2*2;
        float za = (zpart[(size_t)(bb*4+0)*512 + d]*c0 + zpart[(size_t)(bb*4+1)*512 + d]*c1
                  + zpart[(size_t)(bb*4+2)*512 + d]*c2 + zpart[(size_t)(bb*4+3)*512 + d]*c3) * inv;
        float zb = (zpart[(size_t)(bb*4+0)*512 + d+1]*c0 + zpart[(size_t)(bb*4+1)*512 + d+1]*c1
                  + zpart[(size_t)(bb*4+2)*512 + d+1]*c2 + zpart[(size_t)(bb*4+3)*512 + d+1]*c3) * inv;
        za *= sigm(betag[d*64 + bb]);
        zb *= sigm(betag[(d+1)*64 + bb]);
        unsigned int pk = pk2(za, zb);
        zP[d2*64 + bb] = pk;
        *(unsigned int*)((short*)HZ + ((size_t)(t*64+bb)*1024 + 512 + d)) = pk;
      }
    }
    grid.sync();

    // ================= Phase C : gates + LSTM pointwise =================
    {
      const float4* z04 = (const float4*)&wZ[w*2+0][0];
      const float4* z14 = (const float4*)&wZ[w*2+1][0];
      float g0 = whh0 + bsum[w][0];
      float g1 = whh1 + bsum[w][1];
      #pragma unroll 4
      for (int k4 = 0; k4 < 128; k4++){
        float4 c0 = z04[k4];
        float4 c1 = z14[k4];
        unsigned int u0 = zP[(k4*2+0)*64 + lane];
        unsigned int u1 = zP[(k4*2+1)*64 + lane];
        float v0 = lo16(u0), v1 = hi16(u0), v2 = lo16(u1), v3 = hi16(u1);
        g0 += v0*c0.x + v1*c0.y + v2*c0.z + v3*c0.w;
        g1 += v0*c1.x + v1*c1.y + v2*c1.z + v3*c1.w;
      }
      g0 += bf2f(((const unsigned short*)preIH)[((size_t)t*2048 + w*512 + n0+0)*64 + lane]);
      g1 += bf2f(((const unsigned short*)preIH)[((size_t)t*2048 + w*512 + n0+1)*64 + lane]);
      glds[w][0][lane] = g0;
      glds[w][1][lane] = g1;
    }
    __syncthreads();
    if (w < 2){
      int j = w;
      float gi = glds[0][j][lane], gf = glds[1][j][lane];
      float gg = glds[2][j][lane], go = glds[3][j][lane];
      float c_old = cst[j][lane];
      float c_new = sigm(gf)*c_old + sigm(gi)*tanhf(gg);
      float h_new = sigm(go)*tanhf(c_new);
      bool mm = (t < dl);
      float hpub = mm ? h_new : hst[j][lane];
      cst[j][lane] = mm ? c_new : c_old;
      hst[j][lane] = hpub;
      HZ[((size_t)(t*64+lane))*1024 + (n0+j)] = __float2bfloat16(h_new);  // unmasked
    }
    __syncthreads();
    if (w == 0){
      hP[blk*64 + lane] = pk2(hst[0][lane], hst[1][lane]);
    }
    grid.sync();
  }
}

extern "C" void kernel_launch(void* const* d_in, const int* in_sizes, int n_in,
                              void* d_out, int out_size, void* d_ws, size_t ws_size,
                              hipStream_t stream){
  (void)in_sizes; (void)n_in; (void)out_size; (void)ws_size;
  const float* enc    = (const float*)d_in[0];
  const int* captions = (const int*)d_in[1];
  const int* caplen   = (const int*)d_in[2];
  const float* emb    = (const float*)d_in[3];
  const float* W_ea  = (const float*)d_in[4];  const float* b_ea = (const float*)d_in[5];
  const float* W_da  = (const float*)d_in[6];  const float* b_da = (const float*)d_in[7];
  const float* w_fa  = (const float*)d_in[8];  /* b_fa cancels in softmax */
  const float* W_hi  = (const float*)d_in[10]; const float* b_hi = (const float*)d_in[11];
  const float* W_ci  = (const float*)d_in[12]; const float* b_ci = (const float*)d_in[13];
  const float* W_ih  = (const float*)d_in[14]; const float* W_hh = (const float*)d_in[15];
  const float* b_ih  = (const float*)d_in[16]; const float* b_hh = (const float*)d_in[17];
  const float* W_fb  = (const float*)d_in[18]; const float* b_fb = (const float*)d_in[19];
  const float* W_lh  = (const float*)d_in[20]; const float* b_lh = (const float*)d_in[21];
  const float* W_lz  = (const float*)d_in[22]; const float* b_lz = (const float*)d_in[23];
  const float* W_lo  = (const float*)d_in[24]; const float* b_lo = (const float*)d_in[25];
  float* out = (float*)d_out;

  char* p = (char*)d_ws;
  auto alloc = [&](size_t bytes){ char* r = p; p += (bytes + 255) & ~(size_t)255; return r; };
  __hip_bfloat16* enc_bf = (__hip_bfloat16*)alloc(12845056); // 64*196*512
  __hip_bfloat16* att1T  = (__hip_bfloat16*)alloc(12845056); // 64*512*196
  __hip_bfloat16* WeaT   = (__hip_bfloat16*)alloc(524288);   // 512x512
  __hip_bfloat16* W1Tbf  = (__hip_bfloat16*)alloc(3145728);  // 3072x512
  __hip_bfloat16* WihzT  = (__hip_bfloat16*)alloc(2097152);  // 2048x512
  __hip_bfloat16* WtopT  = (__hip_bfloat16*)alloc(2097152);  // 2048x512
  __hip_bfloat16* W2T    = (__hip_bfloat16*)alloc(1048576);  // 512x1024
  __hip_bfloat16* WloT   = (__hip_bfloat16*)alloc(10289152); // 10048x512
  __hip_bfloat16* Erow   = (__hip_bfloat16*)alloc(2031616);  // 1984x512
  __hip_bfloat16* preIH  = (__hip_bfloat16*)alloc(8126464);  // 31x2048x64
  __hip_bfloat16* HZ     = (__hip_bfloat16*)alloc(4063232);  // 1984x1024
  __hip_bfloat16* Ubf    = (__hip_bfloat16*)alloc(2031616);  // 1984x512
  float*        hT0    = (float*)alloc(131072);
  float*        cT0    = (float*)alloc(131072);
  unsigned int* hP     = (unsigned int*)alloc(65536);
  unsigned int* zP     = (unsigned int*)alloc(65536);
  float*        att2g  = (float*)alloc(131072);
  float*        betag  = (float*)alloc(131072);
  float*        zpart  = (float*)alloc(524288);
  float*        msq    = (float*)alloc(2048);

  // ---- setup: casts / transposes / embedding / init ----
  k_cast<<<dim3(6272), dim3(256), 0, stream>>>(enc, enc_bf, 1605632);
  k_trans_bf16<<<dim3(16, 16), dim3(1024), 0, stream>>>(W_ea, WeaT, 512, 512, 512, 512);
  k_trans_bf16<<<dim3(16, 16), dim3(1024), 0, stream>>>(W_da, W1Tbf,            512, 512,  512, 512);
  k_trans_bf16<<<dim3(16, 16), dim3(1024), 0, stream>>>(W_fb, W1Tbf + 512*512,  512, 512,  512, 512);
  k_trans_bf16<<<dim3(64, 16), dim3(1024), 0, stream>>>(W_hh, W1Tbf + 1024*512, 512, 2048, 512, 2048);
  k_trans_bf16<<<dim3(64, 16), dim3(1024), 0, stream>>>(W_ih, WtopT,            512, 2048, 512, 2048);
  k_trans_bf16<<<dim3(64, 16), dim3(1024), 0, stream>>>(W_ih + 512*2048, WihzT, 512, 2048, 512, 2048);
  k_trans_bf16<<<dim3(16, 16), dim3(1024), 0, stream>>>(W_lh, W2T,       512, 512,   1024, 512);
  k_trans_bf16<<<dim3(16, 16), dim3(1024), 0, stream>>>(W_lz, W2T + 512, 512, 512,   1024, 512);
  k_trans_bf16<<<dim3(314, 16), dim3(1024), 0, stream>>>(W_lo, WloT,     512, 10000, 512,  10048);
  k_emb<<<dim3(1984), dim3(512), 0, stream>>>(captions, emb, Erow);
  k_init<<<dim3(64), dim3(512), 0, stream>>>(enc, W_hi, b_hi, W_ci, b_ci, hT0, cT0, hP);

  // att1T = (enc @ W_ea + b_ea)^T-ish layout [b][a][l]
  k_gemm<<<dim3(8, 196), dim3(256), 0, stream>>>(enc_bf, WeaT, 512, 0, 512,
      b_ea, nullptr, nullptr, nullptr, att1T, nullptr);
  // preIH[t][n][b] = emb_t @ W_ih_top
  k_gemm<<<dim3(32, 31), dim3(256), 0, stream>>>(Erow, WtopT, 512, 3, 2048,
      nullptr, nullptr, nullptr, nullptr, preIH, nullptr);

  // ---- the whole 31-step recurrence: one cooperative kernel ----
  {
    const __hip_bfloat16 *a0 = W1Tbf, *a1 = WihzT, *a2 = preIH, *a3 = att1T, *a4 = enc_bf;
    const float *f0 = w_fa, *f1 = b_da, *f2 = b_fb, *f3 = b_ih, *f4 = b_hh, *f5 = hT0, *f6 = cT0;
    unsigned int *u0 = hP, *u1 = zP;
    float *g0 = att2g, *g1 = betag, *g2 = zpart, *g3 = msq;
    __hip_bfloat16 *hz = HZ;
    const int* cl = caplen;
    float* oa = out + PRED_;
    void* args[] = { &a0,&a1,&a2,&a3,&a4, &f0,&f1,&f2,&f3,&f4,&f5,&f6,
                     &u0,&u1, &g0,&g1,&g2,&g3, &hz, &cl, &oa };
    hipLaunchCooperativeKernel((const void*)k_loop, dim3(256), dim3(256), args, 0, stream);
  }

  // U = Erow + HZ @ [W_lh; W_lz] + b_lh + b_lz
  k_gemm<<<dim3(8, 31), dim3(256), 0, stream>>>(HZ, W2T, 1024, 1, 512,
      b_lh, b_lz, Erow, nullptr, Ubf, nullptr);
  // logits = U @ W_lo + b_lo (masked)
  k_gemm<<<dim3(157, 31), dim3(256), 0, stream>>>(Ubf, WloT, 512, 2, 10000,
      b_lo, nullptr, nullptr, caplen, nullptr, out);
}

// Round 7
// 4601.009 us; speedup vs baseline: 1.2449x; 1.2449x over previous
//
#include <hip/hip_runtime.h>
#include <hip/hip_bf16.h>
#include <hip/hip_cooperative_groups.h>

namespace cg = cooperative_groups;

typedef short short8 __attribute__((ext_vector_type(8)));
typedef float floatx4 __attribute__((ext_vector_type(4)));
typedef _Float16 h2v __attribute__((ext_vector_type(2)));

#define B_ 64
#define L_ 196
#define T_ 31
#define PRED_ 19840000ULL

__device__ __forceinline__ float bf2f(unsigned short u){
  union { unsigned int i; float f; } v; v.i = ((unsigned int)u)<<16; return v.f;
}
__device__ __forceinline__ unsigned short bfu(float x){
  union { __hip_bfloat16 h; unsigned short u; } v; v.h = __float2bfloat16(x); return v.u;
}
__device__ __forceinline__ unsigned int pk2(float a, float b){
  return (unsigned int)bfu(a) | ((unsigned int)bfu(b) << 16);
}
__device__ __forceinline__ unsigned int pkh2(float a, float b){
  union { _Float16 h[2]; unsigned int u; } v;
  v.h[0] = (_Float16)a; v.h[1] = (_Float16)b; return v.u;
}
__device__ __forceinline__ float sigm(float x){ return 1.0f/(1.0f+__expf(-x)); }

// packed f16-pair dot product: c += a.lo*b.lo + a.hi*b.hi
__device__ __forceinline__ float dot2(unsigned int a, unsigned int b, float c){
#if __has_builtin(__builtin_amdgcn_fdot2)
  return __builtin_amdgcn_fdot2(__builtin_bit_cast(h2v, a), __builtin_bit_cast(h2v, b), c, false);
#else
  union { unsigned int u; _Float16 h[2]; } x, y; x.u = a; y.u = b;
  return c + (float)x.h[0]*(float)y.h[0] + (float)x.h[1]*(float)y.h[1];
#endif
}

// ---------------- cast f32 -> bf16 (vector x4) ----------------
__global__ __launch_bounds__(256) void k_cast(const float* __restrict__ src,
                                              __hip_bfloat16* __restrict__ dst, int n4){
  int i = blockIdx.x*256 + threadIdx.x;
  if (i < n4){
    const float4 v = *(const float4*)(src + (size_t)i*4);
    size_t o = (size_t)i*4;
    dst[o+0] = __float2bfloat16(v.x);
    dst[o+1] = __float2bfloat16(v.y);
    dst[o+2] = __float2bfloat16(v.z);
    dst[o+3] = __float2bfloat16(v.w);
  }
}

// ------- tiled transpose: src (Kin x Nin) -> dst[n][k] bf16, row stride S --------
__global__ __launch_bounds__(1024) void k_trans_bf16(const float* __restrict__ src,
    __hip_bfloat16* __restrict__ dst, int Kin, int Nin, int S, int Rtot){
  __shared__ float tile[32][33];
  int n0 = blockIdx.x*32, k0 = blockIdx.y*32;
  int x = threadIdx.x & 31, y = threadIdx.x >> 5;
  int k = k0 + y, nn = n0 + x;
  tile[y][x] = (k < Kin && nn < Nin) ? src[(size_t)k*Nin + nn] : 0.0f;
  __syncthreads();
  int n2 = n0 + y, k2 = k0 + x;
  if (n2 < Rtot && k2 < Kin) dst[(size_t)n2*S + k2] = __float2bfloat16(tile[x][y]);
}

// ------- tiled transpose: src (Kin x Nin) -> dst[n][k] f16, row stride S --------
__global__ __launch_bounds__(1024) void k_trans_f16(const float* __restrict__ src,
    _Float16* __restrict__ dst, int Kin, int Nin, int S, int Rtot){
  __shared__ float tile[32][33];
  int n0 = blockIdx.x*32, k0 = blockIdx.y*32;
  int x = threadIdx.x & 31, y = threadIdx.x >> 5;
  int k = k0 + y, nn = n0 + x;
  tile[y][x] = (k < Kin && nn < Nin) ? src[(size_t)k*Nin + nn] : 0.0f;
  __syncthreads();
  int n2 = n0 + y, k2 = k0 + x;
  if (n2 < Rtot && k2 < Kin) dst[(size_t)n2*S + k2] = (_Float16)tile[x][y];
}

// ---------------- embedding gather: Erow[(t*64+b)][m] bf16 -------
__global__ __launch_bounds__(512) void k_emb(const int* __restrict__ captions,
    const float* __restrict__ emb, __hip_bfloat16* __restrict__ Erow){
  int tb = blockIdx.x; int t = tb >> 6; int b = tb & 63; int m = threadIdx.x;
  int cap = captions[b*32 + t];
  Erow[((size_t)(t*64 + b))*512 + m] = __float2bfloat16(emb[(size_t)cap*512 + m]);
}

// ---------------- init h0/c0 (one block per b) ----------------
__global__ __launch_bounds__(512) void k_init(const float* __restrict__ enc,
    const float* __restrict__ Whi, const float* __restrict__ bhi,
    const float* __restrict__ Wci, const float* __restrict__ bci,
    float* __restrict__ hT, float* __restrict__ cT, unsigned int* __restrict__ hP){
  int b = blockIdx.x; int d = threadIdx.x;
  __shared__ float ms[512];
  __shared__ float hs[512];
  const float* eb = enc + (size_t)b*L_*512;
  float s = 0.f;
  for (int l = 0; l < L_; l++) s += eb[(size_t)l*512 + d];
  ms[d] = s * (1.0f/196.0f);
  __syncthreads();
  float a1 = bhi[d], a2 = bci[d];
  #pragma unroll 4
  for (int k = 0; k < 512; k++){
    float mv = ms[k];
    a1 += mv * Whi[(size_t)k*512 + d];
    a2 += mv * Wci[(size_t)k*512 + d];
  }
  float h = tanhf(a1);
  hT[d*64 + b] = h;
  cT[d*64 + b] = tanhf(a2);
  hs[d] = h;
  __syncthreads();
  if (d < 256) hP[d*64 + b] = pkh2(hs[2*d], hs[2*d+1]);
}

// ---------------- MFMA bf16 GEMM: C(64x64 tiles) = A(MxK) @ Bt(NxK)^T ----------------
// mode 0: att1R  -> outB bf16 row-major [r][c] = acc + bias1[c]
// mode 1: U      -> outB bf16 = acc + bias1[c] + bias2[c] + Erow[r][c]
// mode 2: logits -> outF f32  = mask(t<dec_len)*(acc+bias1[c]) at [b][t][c]; 1-D swizzled grid
// mode 3: preIH  -> outB bf16 at [t][c][b] (r -> t=r>>6, b=r&63)
__global__ __launch_bounds__(256) void k_gemm(const __hip_bfloat16* __restrict__ Abf,
    const __hip_bfloat16* __restrict__ Bt, int K, int mode, int Nreal,
    const float* __restrict__ bias1, const float* __restrict__ bias2,
    const __hip_bfloat16* __restrict__ Erow, const int* __restrict__ caplen,
    __hip_bfloat16* __restrict__ outB, float* __restrict__ outF){
  int bx = blockIdx.x, by = blockIdx.y;
  if (mode == 2){
    // bijective XCD-chunk swizzle over 4867 = 157*31 tiles (q=608, r=3)
    int i = bx; int xcd = i & 7; int ii = i >> 3;
    int s = (xcd < 3) ? xcd*609 + ii : 3*609 + (xcd-3)*608 + ii;
    by = s % 31;      // mb
    bx = s / 31;      // nb
  }
  int lane = threadIdx.x & 63; int wv = threadIdx.x >> 6;
  int wr = wv >> 1, wc = wv & 1;
  int r0 = by*64 + wr*32;
  int c0 = bx*64 + wc*32;
  int l15 = lane & 15, lg = lane >> 4;
  const short* Ap = (const short*)Abf;
  const short* Bp = (const short*)Bt;
  floatx4 acc00 = {0,0,0,0}, acc01 = {0,0,0,0}, acc10 = {0,0,0,0}, acc11 = {0,0,0,0};
  size_t ar0 = (size_t)(r0 + l15)*K + lg*8;
  size_t ar1 = ar0 + (size_t)16*K;
  size_t br0 = (size_t)(c0 + l15)*K + lg*8;
  size_t br1 = br0 + (size_t)16*K;
  #pragma unroll 4
  for (int k0 = 0; k0 < K; k0 += 32){
    short8 av0 = *(const short8*)(Ap + ar0 + k0);
    short8 av1 = *(const short8*)(Ap + ar1 + k0);
    short8 bv0 = *(const short8*)(Bp + br0 + k0);
    short8 bv1 = *(const short8*)(Bp + br1 + k0);
    acc00 = __builtin_amdgcn_mfma_f32_16x16x32_bf16(av0, bv0, acc00, 0, 0, 0);
    acc01 = __builtin_amdgcn_mfma_f32_16x16x32_bf16(av0, bv1, acc01, 0, 0, 0);
    acc10 = __builtin_amdgcn_mfma_f32_16x16x32_bf16(av1, bv0, acc10, 0, 0, 0);
    acc11 = __builtin_amdgcn_mfma_f32_16x16x32_bf16(av1, bv1, acc11, 0, 0, 0);
  }
  floatx4 accs[2][2] = {{acc00, acc01}, {acc10, acc11}};
  #pragma unroll
  for (int i = 0; i < 2; i++){
    #pragma unroll
    for (int j = 0; j < 2; j++){
      #pragma unroll
      for (int v = 0; v < 4; v++){
        int r = r0 + 16*i + lg*4 + v;
        int c = c0 + 16*j + l15;
        float val = accs[i][j][v];
        if (mode == 0){
          outB[(size_t)r*512 + c] = __float2bfloat16(val + bias1[c]);
        } else if (mode == 1){
          float e = bf2f(((const unsigned short*)Erow)[(size_t)r*512 + c]);
          outB[(size_t)r*512 + c] = __float2bfloat16(val + bias1[c] + bias2[c] + e);
        } else if (mode == 2){
          if (c < Nreal){
            int t = r >> 6, b = r & 63;
            float mf = (t < caplen[b] - 1) ? 1.f : 0.f;
            outF[((size_t)b*T_ + t)*10000 + c] = (val + bias1[c]) * mf;
          }
        } else {
          outB[((size_t)(r >> 6)*2048 + c)*64 + (r & 63)] = __float2bfloat16(val);
        }
      }
    }
  }
}

// ============ persistent cooperative kernel: the full 31-step recurrence ============
// 256 blocks x 1024 threads (16 waves), 3 grid.syncs per step.
//   A  : 12 row-dots of [att2(512)|beta(512)|whh(2048)] , 8-way K-split, fdot2
//   ATT: blocks 0..63, one per b: e -> softmax -> z -> beta*z (all in-block)
//   C  : 8 gate row-dots (n-pair blk*2..+1), LSTM pointwise; h/c persist in LDS
__global__ __launch_bounds__(1024, 4) void k_loop(
    const unsigned int* __restrict__ W1h,    // [3072][256] f16-pairs: att2|beta|whh
    const unsigned int* __restrict__ Wzh,    // [2048][256] f16-pairs
    const __hip_bfloat16* __restrict__ preIH,// [31][2048][64]
    const __hip_bfloat16* __restrict__ att1R,// [64*196][512]
    const __hip_bfloat16* __restrict__ enc_bf,//[64][196][512]
    const float* __restrict__ wfa,
    const float* __restrict__ b_da, const float* __restrict__ b_fb,
    const float* __restrict__ b_ih, const float* __restrict__ b_hh,
    const float* __restrict__ hT0, const float* __restrict__ cT0,  // [512][64]
    unsigned int* __restrict__ hP,   // [256][64] packed f16 pairs (2k,2k+1)
    unsigned int* __restrict__ zP,   // [256][64]
    float* __restrict__ att2g,       // [512][64]
    float* __restrict__ betag,       // [512][64]
    __hip_bfloat16* __restrict__ HZ, // [1984][1024]
    const int* __restrict__ caplen,
    float* __restrict__ outAlpha)
{
  cg::grid_group grid = cg::this_grid();
  int tid = threadIdx.x, lane = tid & 63, w = tid >> 6;   // w in [0,16)
  int blk = blockIdx.x;

  __shared__ unsigned int wA_l[12][256];   // 12KB resident
  __shared__ unsigned int wZ_l[8][256];    // 8KB resident
  __shared__ float wfa_l[512];
  __shared__ float whh_l[8][64];
  __shared__ float hst[2][64], cst[2][64];
  __shared__ float bsum_l[8];
  __shared__ float biasAB_l[4];
  __shared__ float scr[6144];              // 24KB: A pA[12][8][64] / C pC[8][8][64]
  __shared__ float es[196], ps[196], att2s[512], zsc[512], MS[1];
  __shared__ float glds[8][64];

  // ---- one-time staging ----
  for (int i = tid; i < 3072; i += 1024){
    int ra = i >> 8, kp = i & 255;
    int row;
    if (ra < 4) row = blk*4 + ra;
    else { int rc = ra - 4; row = 1024 + (rc >> 1)*512 + blk*2 + (rc & 1); }
    wA_l[ra][kp] = W1h[(size_t)row*256 + kp];
  }
  for (int i = tid; i < 2048; i += 1024){
    int rc = i >> 8, kp = i & 255;
    int row = (rc >> 1)*512 + blk*2 + (rc & 1);
    wZ_l[rc][kp] = Wzh[(size_t)row*256 + kp];
  }
  for (int i = tid; i < 512; i += 1024) wfa_l[i] = wfa[i];
  if (tid < 128){ int j = tid >> 6;
    hst[j][lane] = hT0[(blk*2+j)*64 + lane];
    cst[j][lane] = cT0[(blk*2+j)*64 + lane];
  }
  if (tid < 8){ int g = tid >> 1, j = tid & 1;
    bsum_l[tid] = b_ih[g*512 + blk*2 + j] + b_hh[g*512 + blk*2 + j];
  }
  if (tid < 4){ int ab = blk*4 + tid;
    biasAB_l[tid] = (ab < 512) ? b_da[ab] : b_fb[ab - 512];
  }
  int dl  = caplen[lane] - 1;                     // used by tid<64 (lane==tid==b)
  int dlb = (blk < 64) ? (caplen[blk] - 1) : 0;   // ATT mask
  __syncthreads();

  for (int t = 0; t < T_; t++){
    // ================= Phase A : h-matvecs (fdot2, 8-way K-split) =================
    {
      int half = w >> 3, kc = w & 7;
      unsigned int hv[32];
      const unsigned int* hp = hP + kc*32*64 + lane;
      #pragma unroll
      for (int i = 0; i < 32; i++) hv[i] = hp[i*64];
      float acc[6] = {0,0,0,0,0,0};
      #pragma unroll
      for (int i = 0; i < 32; i++){
        unsigned int h = hv[i];
        #pragma unroll
        for (int r = 0; r < 6; r++)
          acc[r] = dot2(wA_l[half*6 + r][kc*32 + i], h, acc[r]);
      }
      #pragma unroll
      for (int r = 0; r < 6; r++) scr[((half*6 + r)*8 + kc)*64 + lane] = acc[r];
    }
    __syncthreads();
    if (tid < 768){
      int r = tid >> 6, b = tid & 63;
      float s = 0.f;
      #pragma unroll
      for (int kc = 0; kc < 8; kc++) s += scr[(r*8 + kc)*64 + b];
      if (r < 4){
        int ab = blk*4 + r;
        float v = s + biasAB_l[r];
        if (ab < 512) att2g[ab*64 + b] = v;
        else          betag[(ab-512)*64 + b] = v;
      } else {
        whh_l[r-4][b] = s;
      }
    }
    grid.sync();

    // ================= Phase ATT (blocks 0..63, one per b) =================
    if (blk < 64){
      if (tid < 512){ att2s[tid] = att2g[tid*64 + blk]; zsc[tid] = 0.f; }
      __syncthreads();
      // --- e-pass ---
      {
        float a2r[8], wfr[8];
        #pragma unroll
        for (int u = 0; u < 8; u++){ a2r[u] = att2s[lane*8+u]; wfr[u] = wfa_l[lane*8+u]; }
        #pragma unroll
        for (int i = 0; i < 13; i++){
          int l = w + i*16; int lc = (l < 196) ? l : 195;
          short8 av = *(const short8*)((const short*)att1R + ((size_t)(blk*196 + lc))*512 + lane*8);
          if (l < 196){
            float e = 0.f;
            #pragma unroll
            for (int u = 0; u < 8; u++){
              float v = bf2f((unsigned short)av[u]) + a2r[u];
              v = fmaxf(v, 0.f);
              e += v * wfr[u];
            }
            #pragma unroll
            for (int off = 32; off; off >>= 1) e += __shfl_xor(e, off, 64);
            if (lane == 0) es[l] = e;
          }
        }
      }
      __syncthreads();
      // --- softmax (wave 0) ---
      if (w == 0){
        float v0 = es[lane], v1 = es[lane+64], v2 = es[lane+128];
        float v3 = (lane < 4) ? es[lane+192] : -3e38f;
        float m = fmaxf(fmaxf(v0,v1), fmaxf(v2,v3));
        #pragma unroll
        for (int off = 32; off; off >>= 1) m = fmaxf(m, __shfl_xor(m, off, 64));
        float p0 = __expf(v0-m), p1 = __expf(v1-m), p2 = __expf(v2-m);
        float p3 = (lane < 4) ? __expf(v3-m) : 0.f;
        float s = p0+p1+p2+p3;
        #pragma unroll
        for (int off = 32; off; off >>= 1) s += __shfl_xor(s, off, 64);
        ps[lane] = p0; ps[lane+64] = p1; ps[lane+128] = p2;
        if (lane < 4) ps[lane+192] = p3;
        if (lane == 0) MS[0] = 1.f / s;
      }
      __syncthreads();
      float inv = MS[0];
      if (tid < 196){
        float mf = (t < dlb) ? 1.f : 0.f;
        outAlpha[((size_t)blk*T_ + t)*196 + tid] = ps[tid] * inv * mf;
      }
      // --- z-pass ---
      {
        float zac[8] = {0,0,0,0,0,0,0,0};
        #pragma unroll
        for (int i = 0; i < 13; i++){
          int l = w + i*16; int lc = (l < 196) ? l : 195;
          short8 ev = *(const short8*)((const short*)enc_bf + ((size_t)(blk*196 + lc))*512 + lane*8);
          float pl = (l < 196) ? ps[l] : 0.f;
          #pragma unroll
          for (int u = 0; u < 8; u++) zac[u] += pl * bf2f((unsigned short)ev[u]);
        }
        #pragma unroll
        for (int u = 0; u < 8; u++) atomicAdd(&zsc[lane*8 + u], zac[u]);
      }
      __syncthreads();
      if (tid < 256){
        int d0 = tid*2;
        float za = zsc[d0]   * inv * sigm(betag[(size_t)d0*64 + blk]);
        float zb = zsc[d0+1] * inv * sigm(betag[(size_t)(d0+1)*64 + blk]);
        zP[tid*64 + blk] = pkh2(za, zb);
        *(unsigned int*)((unsigned short*)HZ + ((size_t)(t*64 + blk))*1024 + 512 + d0) = pk2(za, zb);
      }
    }
    grid.sync();

    // ================= Phase C : gates (fdot2) + LSTM pointwise =================
    {
      int half = w >> 3, kc = w & 7;
      unsigned int zv[32];
      const unsigned int* zp = zP + kc*32*64 + lane;
      #pragma unroll
      for (int i = 0; i < 32; i++) zv[i] = zp[i*64];
      float acc[4] = {0,0,0,0};
      #pragma unroll
      for (int i = 0; i < 32; i++){
        unsigned int z = zv[i];
        #pragma unroll
        for (int r = 0; r < 4; r++)
          acc[r] = dot2(wZ_l[half*4 + r][kc*32 + i], z, acc[r]);
      }
      #pragma unroll
      for (int r = 0; r < 4; r++) scr[((half*4 + r)*8 + kc)*64 + lane] = acc[r];
    }
    __syncthreads();
    if (tid < 512){
      int rc = tid >> 6, b = tid & 63;
      int g = rc >> 1, j = rc & 1;
      float s = 0.f;
      #pragma unroll
      for (int kc = 0; kc < 8; kc++) s += scr[(rc*8 + kc)*64 + b];
      s += whh_l[rc][b] + bsum_l[rc]
         + bf2f(((const unsigned short*)preIH)[((size_t)t*2048 + g*512 + blk*2 + j)*64 + b]);
      glds[rc][b] = s;
    }
    __syncthreads();
    if (tid < 64){
      int b = tid;
      float hm2[2];
      #pragma unroll
      for (int j = 0; j < 2; j++){
        float gi = glds[0 + j][b], gf = glds[2 + j][b];
        float gg = glds[4 + j][b], go = glds[6 + j][b];
        float c_old = cst[j][b];
        float c_new = sigm(gf)*c_old + sigm(gi)*tanhf(gg);
        float h_new = sigm(go)*tanhf(c_new);
        bool mm = (t < dl);
        float hm = mm ? h_new : hst[j][b];
        cst[j][b] = mm ? c_new : c_old;
        hst[j][b] = hm;
        hm2[j] = hm;
        ((unsigned short*)HZ)[((size_t)(t*64 + b))*1024 + blk*2 + j] = bfu(h_new);
      }
      hP[blk*64 + b] = pkh2(hm2[0], hm2[1]);
    }
    grid.sync();
  }
}

extern "C" void kernel_launch(void* const* d_in, const int* in_sizes, int n_in,
                              void* d_out, int out_size, void* d_ws, size_t ws_size,
                              hipStream_t stream){
  (void)in_sizes; (void)n_in; (void)out_size; (void)ws_size;
  const float* enc    = (const float*)d_in[0];
  const int* captions = (const int*)d_in[1];
  const int* caplen   = (const int*)d_in[2];
  const float* emb    = (const float*)d_in[3];
  const float* W_ea  = (const float*)d_in[4];  const float* b_ea = (const float*)d_in[5];
  const float* W_da  = (const float*)d_in[6];  const float* b_da = (const float*)d_in[7];
  const float* w_fa  = (const float*)d_in[8];  /* b_fa cancels in softmax */
  const float* W_hi  = (const float*)d_in[10]; const float* b_hi = (const float*)d_in[11];
  const float* W_ci  = (const float*)d_in[12]; const float* b_ci = (const float*)d_in[13];
  const float* W_ih  = (const float*)d_in[14]; const float* W_hh = (const float*)d_in[15];
  const float* b_ih  = (const float*)d_in[16]; const float* b_hh = (const float*)d_in[17];
  const float* W_fb  = (const float*)d_in[18]; const float* b_fb = (const float*)d_in[19];
  const float* W_lh  = (const float*)d_in[20]; const float* b_lh = (const float*)d_in[21];
  const float* W_lz  = (const float*)d_in[22]; const float* b_lz = (const float*)d_in[23];
  const float* W_lo  = (const float*)d_in[24]; const float* b_lo = (const float*)d_in[25];
  float* out = (float*)d_out;

  char* p = (char*)d_ws;
  auto alloc = [&](size_t bytes){ char* r = p; p += (bytes + 255) & ~(size_t)255; return r; };
  __hip_bfloat16* enc_bf = (__hip_bfloat16*)alloc(12845056); // 64*196*512
  __hip_bfloat16* att1R  = (__hip_bfloat16*)alloc(12845056); // [64*196][512]
  __hip_bfloat16* WeaT   = (__hip_bfloat16*)alloc(524288);   // 512x512
  _Float16*       W1h    = (_Float16*)alloc(3145728);        // 3072x512 f16
  _Float16*       Wzh    = (_Float16*)alloc(2097152);        // 2048x512 f16
  __hip_bfloat16* WtopT  = (__hip_bfloat16*)alloc(2097152);  // 2048x512
  __hip_bfloat16* W2T    = (__hip_bfloat16*)alloc(1048576);  // 512x1024
  __hip_bfloat16* WloT   = (__hip_bfloat16*)alloc(10289152); // 10048x512
  __hip_bfloat16* Erow   = (__hip_bfloat16*)alloc(2031616);  // 1984x512
  __hip_bfloat16* preIH  = (__hip_bfloat16*)alloc(8126464);  // 31x2048x64
  __hip_bfloat16* HZ     = (__hip_bfloat16*)alloc(4063232);  // 1984x1024
  __hip_bfloat16* Ubf    = (__hip_bfloat16*)alloc(2031616);  // 1984x512
  float*        hT0    = (float*)alloc(131072);
  float*        cT0    = (float*)alloc(131072);
  unsigned int* hP     = (unsigned int*)alloc(65536);
  unsigned int* zP     = (unsigned int*)alloc(65536);
  float*        att2g  = (float*)alloc(131072);
  float*        betag  = (float*)alloc(131072);

  // ---- setup: casts / transposes / embedding / init ----
  k_cast<<<dim3(6272), dim3(256), 0, stream>>>(enc, enc_bf, 1605632);
  k_trans_f16<<<dim3(16, 16), dim3(1024), 0, stream>>>(W_da, W1h,            512, 512,  512, 512);
  k_trans_f16<<<dim3(16, 16), dim3(1024), 0, stream>>>(W_fb, W1h + 512*512,  512, 512,  512, 512);
  k_trans_f16<<<dim3(64, 16), dim3(1024), 0, stream>>>(W_hh, W1h + 1024*512, 512, 2048, 512, 2048);
  k_trans_f16<<<dim3(64, 16), dim3(1024), 0, stream>>>(W_ih + 512*2048, Wzh, 512, 2048, 512, 2048);
  k_trans_bf16<<<dim3(16, 16), dim3(1024), 0, stream>>>(W_ea, WeaT,      512, 512,   512,  512);
  k_trans_bf16<<<dim3(64, 16), dim3(1024), 0, stream>>>(W_ih, WtopT,     512, 2048,  512,  2048);
  k_trans_bf16<<<dim3(16, 16), dim3(1024), 0, stream>>>(W_lh, W2T,       512, 512,   1024, 512);
  k_trans_bf16<<<dim3(16, 16), dim3(1024), 0, stream>>>(W_lz, W2T + 512, 512, 512,   1024, 512);
  k_trans_bf16<<<dim3(314, 16), dim3(1024), 0, stream>>>(W_lo, WloT,     512, 10000, 512,  10048);
  k_emb<<<dim3(1984), dim3(512), 0, stream>>>(captions, emb, Erow);
  k_init<<<dim3(64), dim3(512), 0, stream>>>(enc, W_hi, b_hi, W_ci, b_ci, hT0, cT0, hP);

  // att1R = enc @ W_ea + b_ea  (row-major [b*196+l][512])
  k_gemm<<<dim3(8, 196), dim3(256), 0, stream>>>(enc_bf, WeaT, 512, 0, 512,
      b_ea, nullptr, nullptr, nullptr, att1R, nullptr);
  // preIH[t][n][b] = emb_t @ W_ih_top
  k_gemm<<<dim3(32, 31), dim3(256), 0, stream>>>(Erow, WtopT, 512, 3, 2048,
      nullptr, nullptr, nullptr, nullptr, preIH, nullptr);

  // ---- the whole 31-step recurrence: one cooperative kernel ----
  {
    const unsigned int *a0 = (const unsigned int*)W1h, *a1 = (const unsigned int*)Wzh;
    const __hip_bfloat16 *a2 = preIH, *a3 = att1R, *a4 = enc_bf;
    const float *f0 = w_fa, *f1 = b_da, *f2 = b_fb, *f3 = b_ih, *f4 = b_hh, *f5 = hT0, *f6 = cT0;
    unsigned int *u0 = hP, *u1 = zP;
    float *g0 = att2g, *g1 = betag;
    __hip_bfloat16 *hz = HZ;
    const int* cl = caplen;
    float* oa = out + PRED_;
    void* args[] = { &a0,&a1,&a2,&a3,&a4, &f0,&f1,&f2,&f3,&f4,&f5,&f6,
                     &u0,&u1, &g0,&g1, &hz, &cl, &oa };
    hipLaunchCooperativeKernel((const void*)k_loop, dim3(256), dim3(1024), args, 0, stream);
  }

  // U = Erow + HZ @ [W_lh; W_lz] + b_lh + b_lz
  k_gemm<<<dim3(8, 31), dim3(256), 0, stream>>>(HZ, W2T, 1024, 1, 512,
      b_lh, b_lz, Erow, nullptr, Ubf, nullptr);
  // logits = U @ W_lo + b_lo (masked), 1-D XCD-swizzled grid of 157*31 tiles
  k_gemm<<<dim3(4867), dim3(256), 0, stream>>>(Ubf, WloT, 512, 2, 10000,
      b_lo, nullptr, nullptr, caplen, nullptr, out);
}